// Round 1
// baseline (7537.529 us; speedup 1.0000x reference)
//
#include <hip/hip_runtime.h>
#include <hip/hip_bf16.h>

using bf16 = __hip_bfloat16;

constexpr int kT  = 256;
constexpr int kB  = 256;
constexpr int kD  = 512;
constexpr int kH  = 8;
constexpr int kDK = 64;
constexpr int kNG = 16;
constexpr int kID = kH * kDK;  // 512

// Kernel 1: one block per (t, h). Each thread owns one batch row i.
// Computes Q/K/V row-slices for head h (f32 FMA, W reads are wave-uniform ->
// scalar loads), stages them in LDS as bf16, then does group-restricted
// online-softmax attention (groups are contiguous since group_ids is sorted).
// Writes pre-Wo attention output into d_out (f32), layout [t][i][h*64+d].
__global__ __launch_bounds__(256) void qkv_attn_kernel(
    const float* __restrict__ hs,   // [T][B][D]
    const int*   __restrict__ gid,  // [B], sorted
    const float* __restrict__ Wq,   // [D][512]
    const float* __restrict__ Wk,
    const float* __restrict__ Wv,
    float*       __restrict__ out)  // [T][B][512]
{
    const int t = blockIdx.x;
    const int h = blockIdx.y;
    const int i = threadIdx.x;  // batch row

    __shared__ bf16 kv[3][kB][kDK + 4];   // q,k,v tiles, padded (104 KB)
    __shared__ int glo[kNG], ghi[kNG];

    if (i < kNG) { glo[i] = kB; ghi[i] = -1; }
    __syncthreads();
    const int g = gid[i];
    atomicMin(&glo[g], i);
    atomicMax(&ghi[g], i);

    const float* __restrict__ hsrow = hs + ((size_t)t * kB + i) * kD;

    // ---- QKV projection for row i, head-h column slice (64 cols each) ----
    #pragma unroll 1
    for (int m = 0; m < 3; ++m) {
        const float* __restrict__ W = (m == 0) ? Wq : (m == 1) ? Wk : Wv;
        #pragma unroll 1
        for (int cb = 0; cb < kDK; cb += 32) {
            float acc[32];
            #pragma unroll
            for (int c = 0; c < 32; ++c) acc[c] = 0.0f;
            #pragma unroll 1
            for (int d0 = 0; d0 < kD; d0 += 64) {
                float hreg[64];
                #pragma unroll
                for (int dd = 0; dd < 64; dd += 4) {
                    const float4 v4 = *reinterpret_cast<const float4*>(hsrow + d0 + dd);
                    hreg[dd + 0] = v4.x; hreg[dd + 1] = v4.y;
                    hreg[dd + 2] = v4.z; hreg[dd + 3] = v4.w;
                }
                #pragma unroll
                for (int dd = 0; dd < 64; ++dd) {
                    // uniform address across lanes -> s_load + SGPR operand FMA
                    const float* __restrict__ wrow =
                        W + (size_t)(d0 + dd) * kID + h * kDK + cb;
                    #pragma unroll
                    for (int c = 0; c < 32; ++c)
                        acc[c] = fmaf(hreg[dd], wrow[c], acc[c]);
                }
            }
            #pragma unroll
            for (int c = 0; c < 32; ++c)
                kv[m][i][cb + c] = __float2bfloat16(acc[c]);
        }
    }
    __syncthreads();

    // ---- group-restricted attention for row i (contiguous range) ----
    const int lo = glo[g];
    const int hi = ghi[g];

    float q[kDK];
    #pragma unroll
    for (int d = 0; d < kDK; ++d) q[d] = __bfloat162float(kv[0][i][d]);

    float o[kDK];
    #pragma unroll
    for (int d = 0; d < kDK; ++d) o[d] = 0.0f;
    float mrun = -3.0e38f;
    float lrun = 0.0f;

    #pragma unroll 1
    for (int j = lo; j <= hi; ++j) {
        float s = 0.0f;
        #pragma unroll
        for (int d = 0; d < kDK; ++d)
            s = fmaf(q[d], __bfloat162float(kv[1][j][d]), s);
        s *= 0.125f;  // 1/sqrt(64)
        const float mn   = fmaxf(mrun, s);
        const float corr = __expf(mrun - mn);
        const float p    = __expf(s - mn);
        lrun = lrun * corr + p;
        #pragma unroll
        for (int d = 0; d < kDK; ++d)
            o[d] = fmaf(o[d], corr, p * __bfloat162float(kv[2][j][d]));
        mrun = mn;
    }

    const float inv = 1.0f / lrun;
    float* __restrict__ orow = out + ((size_t)t * kB + i) * kID + h * kDK;
    #pragma unroll
    for (int d = 0; d < kDK; d += 4) {
        float4 v4;
        v4.x = o[d + 0] * inv; v4.y = o[d + 1] * inv;
        v4.z = o[d + 2] * inv; v4.w = o[d + 3] * inv;
        *reinterpret_cast<float4*>(orow + d) = v4;
    }
}

// Kernel 2: in-place out = out @ Wo. One block per 64 rows: stage rows in LDS,
// each thread owns 4 output cols x 32 rows so each Wo float4 is loaded once
// per wave-pass and reused across 32 rows in registers.
__global__ __launch_bounds__(256) void oproj_kernel(
    const float* __restrict__ Wo,   // [512][512]
    float*       __restrict__ out)  // [T*B][512], in-place
{
    __shared__ float x[64][kID];    // 128 KB
    const int tid = threadIdx.x;
    float* __restrict__ base = out + (size_t)blockIdx.x * 64 * kID;

    #pragma unroll 1
    for (int idx = tid; idx < 64 * kID; idx += 256)
        x[idx >> 9][idx & (kID - 1)] = base[idx];
    __syncthreads();

    const int c0 = (tid & 127) * 4;   // 4 consecutive output cols
    const int r0 = (tid >> 7) * 32;   // 32 rows

    float acc[32][4];
    #pragma unroll
    for (int rr = 0; rr < 32; ++rr) {
        #pragma unroll
        for (int c = 0; c < 4; ++c) acc[rr][c] = 0.0f;
    }

    #pragma unroll 1
    for (int d = 0; d < kID; d += 4) {
        const float4 w0 = *reinterpret_cast<const float4*>(Wo + (size_t)(d + 0) * kD + c0);
        const float4 w1 = *reinterpret_cast<const float4*>(Wo + (size_t)(d + 1) * kD + c0);
        const float4 w2 = *reinterpret_cast<const float4*>(Wo + (size_t)(d + 2) * kD + c0);
        const float4 w3 = *reinterpret_cast<const float4*>(Wo + (size_t)(d + 3) * kD + c0);
        #pragma unroll
        for (int rr = 0; rr < 32; ++rr) {
            const float4 xv = *reinterpret_cast<const float4*>(&x[r0 + rr][d]);
            acc[rr][0] = fmaf(xv.x, w0.x, acc[rr][0]);
            acc[rr][0] = fmaf(xv.y, w1.x, acc[rr][0]);
            acc[rr][0] = fmaf(xv.z, w2.x, acc[rr][0]);
            acc[rr][0] = fmaf(xv.w, w3.x, acc[rr][0]);
            acc[rr][1] = fmaf(xv.x, w0.y, acc[rr][1]);
            acc[rr][1] = fmaf(xv.y, w1.y, acc[rr][1]);
            acc[rr][1] = fmaf(xv.z, w2.y, acc[rr][1]);
            acc[rr][1] = fmaf(xv.w, w3.y, acc[rr][1]);
            acc[rr][2] = fmaf(xv.x, w0.z, acc[rr][2]);
            acc[rr][2] = fmaf(xv.y, w1.z, acc[rr][2]);
            acc[rr][2] = fmaf(xv.z, w2.z, acc[rr][2]);
            acc[rr][2] = fmaf(xv.w, w3.z, acc[rr][2]);
            acc[rr][3] = fmaf(xv.x, w0.w, acc[rr][3]);
            acc[rr][3] = fmaf(xv.y, w1.w, acc[rr][3]);
            acc[rr][3] = fmaf(xv.z, w2.w, acc[rr][3]);
            acc[rr][3] = fmaf(xv.w, w3.w, acc[rr][3]);
        }
    }

    #pragma unroll
    for (int rr = 0; rr < 32; ++rr) {
        float4 v4;
        v4.x = acc[rr][0]; v4.y = acc[rr][1]; v4.z = acc[rr][2]; v4.w = acc[rr][3];
        *reinterpret_cast<float4*>(&base[(size_t)(r0 + rr) * kID + c0]) = v4;
    }
}

extern "C" void kernel_launch(void* const* d_in, const int* in_sizes, int n_in,
                              void* d_out, int out_size, void* d_ws, size_t ws_size,
                              hipStream_t stream) {
    const float* hs  = (const float*)d_in[0];
    const int*   gid = (const int*)  d_in[1];
    const float* Wq  = (const float*)d_in[2];
    const float* Wk  = (const float*)d_in[3];
    const float* Wv  = (const float*)d_in[4];
    const float* Wo  = (const float*)d_in[5];
    float* out = (float*)d_out;

    qkv_attn_kernel<<<dim3(kT, kH), 256, 0, stream>>>(hs, gid, Wq, Wk, Wv, out);
    oproj_kernel<<<dim3((kT * kB) / 64), 256, 0, stream>>>(Wo, out);
}

// Round 2
// 443.459 us; speedup vs baseline: 16.9971x; 16.9971x over previous
//
#include <hip/hip_runtime.h>
#include <hip/hip_bf16.h>

typedef __attribute__((ext_vector_type(8))) short short8;
typedef __attribute__((ext_vector_type(4))) short short4v;
typedef __attribute__((ext_vector_type(4))) float f32x4;

#define MFMA16(a, b, c) __builtin_amdgcn_mfma_f32_16x16x32_bf16(a, b, c, 0, 0, 0)

__device__ __forceinline__ unsigned short f2bf(float f) {
    union { float f; unsigned u; } v; v.f = f;
    unsigned r = (v.u + 0x7FFFu + ((v.u >> 16) & 1u)) >> 16;
    return (unsigned short)r;
}

__device__ __forceinline__ short8 pack8(float4 a, float4 b) {
    short8 p;
    p[0] = (short)f2bf(a.x); p[1] = (short)f2bf(a.y);
    p[2] = (short)f2bf(a.z); p[3] = (short)f2bf(a.w);
    p[4] = (short)f2bf(b.x); p[5] = (short)f2bf(b.y);
    p[6] = (short)f2bf(b.z); p[7] = (short)f2bf(b.w);
    return p;
}

// ---------------------------------------------------------------------------
// Kernel 1: fused QKV projection + group-restricted flash attention.
// One block per (t, h); 512 threads = 8 waves; wave w owns Q rows [32w,32w+32).
// LDS layouts (all row strides are multiples of 16 B for ds_read_b128, and
// chosen so A/B-fragment reads are <=2-way bank conflicts):
//   Qs/Ks [256][72] bf16 (144 B rows), Vt [64][264] (V transposed, 528 B rows),
//   Wt [3][64][40] (W transposed, 80 B rows), XP union: X stage [256][40] /
//   P tile [256][72].
// ---------------------------------------------------------------------------
__global__ __launch_bounds__(512) void qkv_attn_mfma(
    const float* __restrict__ hs,   // [256][256][512]
    const int*   __restrict__ gid,  // [256] sorted
    const float* __restrict__ Wq,   // [512][512]
    const float* __restrict__ Wk,
    const float* __restrict__ Wv,
    float*       __restrict__ out)  // [256][256][512] (attn out, pre-Wo)
{
    __shared__ unsigned short Qs[256][72];
    __shared__ unsigned short Ks[256][72];
    __shared__ unsigned short Vts[64][264];
    __shared__ unsigned short Wts[3][64][40];
    __shared__ unsigned short XPs[256 * 72];
    __shared__ int sgid[256];
    __shared__ int glo[16], ghi[16];

    // XCD-locality swizzle: the 8 blocks sharing t get bids 8 apart -> same
    // XCD (bid%8 invariant), co-resident -> X_t hits L2 for 7/8 blocks.
    const int bid = blockIdx.x;
    const int h   = (bid & 63) >> 3;
    const int t   = (bid >> 6) * 8 + (bid & 7);

    const int tid  = threadIdx.x;
    const int lane = tid & 63;
    const int w    = tid >> 6;
    const int l15  = lane & 15;
    const int hi4  = lane >> 4;
    const int wrow = w * 32;

    if (tid < 16) { glo[tid] = 256; ghi[tid] = -1; }
    __syncthreads();
    if (tid < 256) {
        const int g = gid[tid];
        sgid[tid] = g;
        atomicMin(&glo[g], tid);
        atomicMax(&ghi[g], tid);
    }

    const float* __restrict__ Xbase = hs + (size_t)t * (256 * 512);
    const float* Wm[3] = {Wq, Wk, Wv};

    f32x4 acc[3][2][4];
    #pragma unroll
    for (int m = 0; m < 3; ++m)
        #pragma unroll
        for (int a = 0; a < 2; ++a)
            #pragma unroll
            for (int n = 0; n < 4; ++n)
                acc[m][a][n] = (f32x4){0.f, 0.f, 0.f, 0.f};

    const int xi = tid >> 1, xf = tid & 1;      // X stage: row, 16-float half
    const int wn = tid & 63, wkq = tid >> 6;    // W stage: col, 4-row quad

    for (int kb = 0; kb < 512; kb += 32) {
        // ---- stage X chunk [256][32] f32 -> bf16 LDS ----
        {
            const float* src = Xbase + (size_t)xi * 512 + kb + xf * 16;
            const float4 f0 = *(const float4*)(src + 0);
            const float4 f1 = *(const float4*)(src + 4);
            const float4 f2 = *(const float4*)(src + 8);
            const float4 f3 = *(const float4*)(src + 12);
            *(short8*)&XPs[xi * 40 + xf * 16 + 0] = pack8(f0, f1);
            *(short8*)&XPs[xi * 40 + xf * 16 + 8] = pack8(f2, f3);
        }
        // ---- stage W chunks [32][64] -> transposed Wt[n][k] bf16 ----
        #pragma unroll
        for (int m = 0; m < 3; ++m) {
            const float* wp = Wm[m] + (size_t)(kb + wkq * 4) * 512 + h * 64 + wn;
            short4v pw;
            pw[0] = (short)f2bf(wp[0]);
            pw[1] = (short)f2bf(wp[512]);
            pw[2] = (short)f2bf(wp[1024]);
            pw[3] = (short)f2bf(wp[1536]);
            *(short4v*)&Wts[m][wn][wkq * 4] = pw;
        }
        __syncthreads();

        // ---- MFMA: 3 mats x (2 mrep x 4 nrep) ----
        const short8 af0 = *(const short8*)&XPs[(wrow + l15) * 40 + hi4 * 8];
        const short8 af1 = *(const short8*)&XPs[(wrow + 16 + l15) * 40 + hi4 * 8];
        #pragma unroll
        for (int m = 0; m < 3; ++m) {
            #pragma unroll
            for (int n = 0; n < 4; ++n) {
                const short8 bf = *(const short8*)&Wts[m][n * 16 + l15][hi4 * 8];
                acc[m][0][n] = MFMA16(af0, bf, acc[m][0][n]);
                acc[m][1][n] = MFMA16(af1, bf, acc[m][1][n]);
            }
        }
        __syncthreads();
    }

    // ---- epilogue: scatter C-frags (row=4*hi+reg, col=l15) into LDS ----
    #pragma unroll
    for (int a = 0; a < 2; ++a) {
        #pragma unroll
        for (int n = 0; n < 4; ++n) {
            #pragma unroll
            for (int r = 0; r < 4; ++r) {
                const int row = wrow + a * 16 + hi4 * 4 + r;
                const int col = n * 16 + l15;
                Qs[row][col] = f2bf(acc[0][a][n][r]);
                Ks[row][col] = f2bf(acc[1][a][n][r]);
                Vts[col][row] = f2bf(acc[2][a][n][r]);
            }
        }
    }
    __syncthreads();

    // ---- group-restricted flash attention, per-wave private rows ----
    int rg[2][4];
    #pragma unroll
    for (int a = 0; a < 2; ++a)
        #pragma unroll
        for (int r = 0; r < 4; ++r)
            rg[a][r] = sgid[wrow + a * 16 + hi4 * 4 + r];
    const int klo = glo[sgid[wrow]];
    const int khi = ghi[sgid[wrow + 31]];

    short8 qf[2][2];
    #pragma unroll
    for (int a = 0; a < 2; ++a)
        #pragma unroll
        for (int ks = 0; ks < 2; ++ks)
            qf[a][ks] = *(const short8*)&Qs[wrow + a * 16 + l15][ks * 32 + hi4 * 8];

    f32x4 o[2][4];
    float mrun[2][4], lrun[2][4];
    #pragma unroll
    for (int a = 0; a < 2; ++a)
        #pragma unroll
        for (int n = 0; n < 4; ++n)
            o[a][n] = (f32x4){0.f, 0.f, 0.f, 0.f};
    #pragma unroll
    for (int a = 0; a < 2; ++a)
        #pragma unroll
        for (int r = 0; r < 4; ++r) { mrun[a][r] = -3.0e38f; lrun[a][r] = 0.f; }

    for (int kc = klo & ~63; kc <= khi; kc += 64) {
        // S chunk = Q @ K^T  (A=Q frags, B=K frags; both A-shaped reads)
        f32x4 sfr[2][4];
        #pragma unroll
        for (int n = 0; n < 4; ++n) {
            const int krow = kc + n * 16 + l15;
            const short8 kf0 = *(const short8*)&Ks[krow][hi4 * 8];
            const short8 kf1 = *(const short8*)&Ks[krow][32 + hi4 * 8];
            #pragma unroll
            for (int a = 0; a < 2; ++a) {
                f32x4 z = (f32x4){0.f, 0.f, 0.f, 0.f};
                z = MFMA16(qf[a][0], kf0, z);
                z = MFMA16(qf[a][1], kf1, z);
                sfr[a][n] = z;
            }
        }
        int cg[4];
        #pragma unroll
        for (int n = 0; n < 4; ++n) cg[n] = sgid[kc + n * 16 + l15];

        #pragma unroll
        for (int a = 0; a < 2; ++a) {
            #pragma unroll
            for (int r = 0; r < 4; ++r) {
                const int gr = rg[a][r];
                float sv[4];
                float smax = -3.0e38f;
                #pragma unroll
                for (int n = 0; n < 4; ++n) {
                    float x = sfr[a][n][r] * 0.125f;   // 1/sqrt(64)
                    x = (cg[n] == gr) ? x : -3.0e38f;
                    sv[n] = x;
                    smax = fmaxf(smax, x);
                }
                smax = fmaxf(smax, __shfl_xor(smax, 1));
                smax = fmaxf(smax, __shfl_xor(smax, 2));
                smax = fmaxf(smax, __shfl_xor(smax, 4));
                smax = fmaxf(smax, __shfl_xor(smax, 8));
                const float newm = fmaxf(mrun[a][r], smax);
                const float corr = __expf(mrun[a][r] - newm);
                float ps = 0.f;
                unsigned short pb[4];
                #pragma unroll
                for (int n = 0; n < 4; ++n) {
                    // guard: masked lanes must yield p=0 even when newm==-3e38
                    const float p = (sv[n] > -1.0e38f) ? __expf(sv[n] - newm) : 0.f;
                    ps += p;
                    pb[n] = f2bf(p);
                }
                ps += __shfl_xor(ps, 1); ps += __shfl_xor(ps, 2);
                ps += __shfl_xor(ps, 4); ps += __shfl_xor(ps, 8);
                lrun[a][r] = lrun[a][r] * corr + ps;
                mrun[a][r] = newm;
                #pragma unroll
                for (int n = 0; n < 4; ++n) o[a][n][r] *= corr;
                const int prow = wrow + a * 16 + hi4 * 4 + r;
                #pragma unroll
                for (int n = 0; n < 4; ++n)
                    XPs[prow * 72 + n * 16 + l15] = pb[n];
            }
        }
        // PV: O += P @ V  (A=P from LDS, B=V from transposed Vt)
        #pragma unroll
        for (int a = 0; a < 2; ++a) {
            const short8 pa0 = *(const short8*)&XPs[(wrow + a * 16 + l15) * 72 + hi4 * 8];
            const short8 pa1 = *(const short8*)&XPs[(wrow + a * 16 + l15) * 72 + 32 + hi4 * 8];
            #pragma unroll
            for (int n = 0; n < 4; ++n) {
                const short8 vb0 = *(const short8*)&Vts[n * 16 + l15][kc + hi4 * 8];
                const short8 vb1 = *(const short8*)&Vts[n * 16 + l15][kc + 32 + hi4 * 8];
                o[a][n] = MFMA16(pa0, vb0, o[a][n]);
                o[a][n] = MFMA16(pa1, vb1, o[a][n]);
            }
        }
    }

    float* __restrict__ op = out + (size_t)t * (256 * 512) + h * 64;
    #pragma unroll
    for (int a = 0; a < 2; ++a) {
        #pragma unroll
        for (int r = 0; r < 4; ++r) {
            const int row = wrow + a * 16 + hi4 * 4 + r;
            const float inv = 1.0f / lrun[a][r];
            #pragma unroll
            for (int n = 0; n < 4; ++n)
                op[(size_t)row * 512 + n * 16 + l15] = o[a][n][r] * inv;
        }
    }
}

// ---------------------------------------------------------------------------
// Kernel 2: in-place out = out @ Wo, bf16 MFMA. Block tile = 128 rows x FULL
// 512 cols (full width keeps the in-place read/write block-local: each block
// reads only the rows it later writes; a column-split would race).
// 512 threads = 8 waves (2x4), wave tile 64x128 (mrep 4 x nrep 8).
// ---------------------------------------------------------------------------
__global__ __launch_bounds__(512) void oproj_mfma(
    const float* __restrict__ Wo,   // [512][512]
    float*       __restrict__ out)  // [65536][512] in-place
{
    __shared__ unsigned short As[128 * 40];    // A tile [128][32] padded
    __shared__ unsigned short Bts[512 * 40];   // Wo^T tile [512 n][32 k] padded

    const int tid  = threadIdx.x;
    const int lane = tid & 63;
    const int w    = tid >> 6;
    const int l15  = lane & 15;
    const int hi4  = lane >> 4;
    const int wr   = w >> 2;        // 0..1
    const int wc   = w & 3;         // 0..3
    const size_t r0 = (size_t)blockIdx.x * 128;

    f32x4 acc[4][8];
    #pragma unroll
    for (int m = 0; m < 4; ++m)
        #pragma unroll
        for (int n = 0; n < 8; ++n)
            acc[m][n] = (f32x4){0.f, 0.f, 0.f, 0.f};

    const int ai = tid >> 2, aq = tid & 3;   // A stage: row, 8-float quarter
    const int bn = tid;                      // B stage: one Wo column each

    for (int kb = 0; kb < 512; kb += 32) {
        {
            const float* src = out + (r0 + ai) * 512 + kb + aq * 8;
            const float4 f0 = *(const float4*)(src + 0);
            const float4 f1 = *(const float4*)(src + 4);
            *(short8*)&As[ai * 40 + aq * 8] = pack8(f0, f1);
        }
        {
            const float* src = Wo + (size_t)kb * 512 + bn;
            #pragma unroll
            for (int q = 0; q < 4; ++q) {
                short8 p;
                #pragma unroll
                for (int j = 0; j < 8; ++j)
                    p[j] = (short)f2bf(src[(size_t)(q * 8 + j) * 512]);
                *(short8*)&Bts[bn * 40 + q * 8] = p;
            }
        }
        __syncthreads();

        short8 afr[4];
        #pragma unroll
        for (int m = 0; m < 4; ++m)
            afr[m] = *(const short8*)&As[(wr * 64 + m * 16 + l15) * 40 + hi4 * 8];
        #pragma unroll
        for (int n = 0; n < 8; ++n) {
            const short8 bfr = *(const short8*)&Bts[(wc * 128 + n * 16 + l15) * 40 + hi4 * 8];
            #pragma unroll
            for (int m = 0; m < 4; ++m)
                acc[m][n] = MFMA16(afr[m], bfr, acc[m][n]);
        }
        __syncthreads();
    }

    #pragma unroll
    for (int m = 0; m < 4; ++m)
        #pragma unroll
        for (int n = 0; n < 8; ++n)
            #pragma unroll
            for (int r = 0; r < 4; ++r)
                out[(r0 + wr * 64 + m * 16 + hi4 * 4 + r) * 512 + wc * 128 + n * 16 + l15] =
                    acc[m][n][r];
}

extern "C" void kernel_launch(void* const* d_in, const int* in_sizes, int n_in,
                              void* d_out, int out_size, void* d_ws, size_t ws_size,
                              hipStream_t stream) {
    const float* hs  = (const float*)d_in[0];
    const int*   gid = (const int*)  d_in[1];
    const float* Wq  = (const float*)d_in[2];
    const float* Wk  = (const float*)d_in[3];
    const float* Wv  = (const float*)d_in[4];
    const float* Wo  = (const float*)d_in[5];
    float* outp = (float*)d_out;

    qkv_attn_mfma<<<2048, 512, 0, stream>>>(hs, gid, Wq, Wk, Wv, outp);
    oproj_mfma<<<512, 512, 0, stream>>>(Wo, outp);
}

// Round 3
// 338.644 us; speedup vs baseline: 22.2580x; 1.3095x over previous
//
#include <hip/hip_runtime.h>
#include <hip/hip_bf16.h>

typedef __attribute__((ext_vector_type(8))) short short8;
typedef __attribute__((ext_vector_type(4))) short short4v;
typedef __attribute__((ext_vector_type(4))) float f32x4;

#define MFMA16(a, b, c) __builtin_amdgcn_mfma_f32_16x16x32_bf16(a, b, c, 0, 0, 0)

__device__ __forceinline__ unsigned short f2bf(float f) {
    __hip_bfloat16 h = __float2bfloat16(f);
    union { __hip_bfloat16 h; unsigned short u; } v;
    v.h = h;
    return v.u;
}

__device__ __forceinline__ short8 pack8(float4 a, float4 b) {
    short8 p;
    p[0] = (short)f2bf(a.x); p[1] = (short)f2bf(a.y);
    p[2] = (short)f2bf(a.z); p[3] = (short)f2bf(a.w);
    p[4] = (short)f2bf(b.x); p[5] = (short)f2bf(b.y);
    p[6] = (short)f2bf(b.z); p[7] = (short)f2bf(b.w);
    return p;
}

// ---------------------------------------------------------------------------
// Weight prep: wt[m][n][k] = W_m[k][n] as bf16, m in {Wq,Wk,Wv,Wo}.
// LDS-tiled transpose, both sides coalesced.
// ---------------------------------------------------------------------------
__global__ __launch_bounds__(256) void wprep(
    const float* __restrict__ Wq, const float* __restrict__ Wk,
    const float* __restrict__ Wv, const float* __restrict__ Wo,
    unsigned short* __restrict__ wt)
{
    __shared__ float tile[64][65];
    const int bid = blockIdx.x;
    const int m = bid >> 6, tb = bid & 63;
    const int kr = (tb >> 3) << 6, nc = (tb & 7) << 6;
    const float* W = (m == 0) ? Wq : (m == 1) ? Wk : (m == 2) ? Wv : Wo;
    const int tid = threadIdx.x;
    for (int i = tid; i < 4096; i += 256)
        tile[i >> 6][i & 63] = W[(size_t)(kr + (i >> 6)) * 512 + nc + (i & 63)];
    __syncthreads();
    unsigned short* dst = wt + (size_t)m * 262144;
    for (int i = tid; i < 4096; i += 256)
        dst[(size_t)(nc + (i >> 6)) * 512 + kr + (i & 63)] = f2bf(tile[i & 63][i >> 6]);
}

// ---------------------------------------------------------------------------
// Kernel 1: fused QKV projection + group-restricted flash attention.
// One block per (t, h); 1024 threads = 16 waves (4/SIMD); wave w owns 16 rows.
// Register-prefetched staging; W from pre-transposed bf16 (wt) when available.
// ---------------------------------------------------------------------------
__global__ __launch_bounds__(1024, 4) void qkv_attn_mfma(
    const float* __restrict__ hs,   // [256][256][512]
    const int*   __restrict__ gid,  // [256] sorted
    const float* __restrict__ Wq, const float* __restrict__ Wk,
    const float* __restrict__ Wv,
    const unsigned short* __restrict__ wt,   // [3][512][512] bf16 W^T or null
    unsigned short* __restrict__ abuf,       // [256][256][512] bf16 attn-out or null
    float*       __restrict__ out)           // [256][256][512] f32 attn-out
{
    __shared__ unsigned short Qs[256][72];
    __shared__ unsigned short Ks[256][72];
    __shared__ unsigned short Vts[64][264];
    __shared__ unsigned short Wts[3][64][40];
    __shared__ unsigned short XPs[256 * 72];
    __shared__ int sgid[256];
    __shared__ int glo[16], ghi[16];

    // XCD swizzle: 8 blocks sharing t land 8 apart (same XCD) within one
    // 64-block dispatch window -> X_t L2-shared across its 8 heads.
    const int bid = blockIdx.x;
    const int h   = (bid & 63) >> 3;
    const int t   = ((bid >> 6) << 3) + (bid & 7);

    const int tid  = threadIdx.x;
    const int lane = tid & 63;
    const int w    = tid >> 6;       // 0..15
    const int l15  = lane & 15;
    const int hi4  = lane >> 4;
    const int wrow = w << 4;         // 16 rows per wave

    if (tid < 16) { glo[tid] = 256; ghi[tid] = -1; }
    __syncthreads();
    if (tid < 256) {
        const int g = gid[tid];
        sgid[tid] = g;
        atomicMin(&glo[g], tid);
        atomicMax(&ghi[g], tid);
    }

    const float* __restrict__ Xbase = hs + (size_t)t * (256 * 512);

    f32x4 acc[3][4];
    #pragma unroll
    for (int m = 0; m < 3; ++m)
        #pragma unroll
        for (int n = 0; n < 4; ++n)
            acc[m][n] = (f32x4){0.f, 0.f, 0.f, 0.f};

    // staging assignments
    const int xi = tid >> 2, xq = tid & 3;     // X: row, 8-col octet
    const bool doW = tid < 768;
    const int wrh = tid >> 2;                  // 0..191 when doW
    const int wq  = tid & 3;
    const int wm  = wrh >> 6;                  // 0..2
    const int wn  = wrh & 63;
    const float* __restrict__ Wsl = (wm == 0) ? Wq : (wm == 1) ? Wk : Wv;

    float4 xf0, xf1;
    short8 wreg;
    {
        const float* s = Xbase + (size_t)xi * 512 + xq * 8;
        xf0 = *(const float4*)s; xf1 = *(const float4*)(s + 4);
        if (doW) {
            if (wt) {
                wreg = *(const short8*)(wt + ((size_t)wm * 512 + h * 64 + wn) * 512 + wq * 8);
            } else {
                #pragma unroll
                for (int j = 0; j < 8; ++j)
                    wreg[j] = (short)f2bf(Wsl[(size_t)(wq * 8 + j) * 512 + h * 64 + wn]);
            }
        }
    }

    for (int kb = 0; kb < 512; kb += 32) {
        *(short8*)&XPs[xi * 40 + xq * 8] = pack8(xf0, xf1);
        if (doW) *(short8*)&Wts[wm][wn][wq * 8] = wreg;
        __syncthreads();
        if (kb < 480) {  // prefetch next K-step under the MFMAs
            const int kn = kb + 32;
            const float* s = Xbase + (size_t)xi * 512 + kn + xq * 8;
            xf0 = *(const float4*)s; xf1 = *(const float4*)(s + 4);
            if (doW) {
                if (wt) {
                    wreg = *(const short8*)(wt + ((size_t)wm * 512 + h * 64 + wn) * 512 + kn + wq * 8);
                } else {
                    #pragma unroll
                    for (int j = 0; j < 8; ++j)
                        wreg[j] = (short)f2bf(Wsl[(size_t)(kn + wq * 8 + j) * 512 + h * 64 + wn]);
                }
            }
        }
        const short8 af = *(const short8*)&XPs[(wrow + l15) * 40 + hi4 * 8];
        __builtin_amdgcn_s_setprio(1);
        #pragma unroll
        for (int m = 0; m < 3; ++m) {
            #pragma unroll
            for (int n = 0; n < 4; ++n) {
                const short8 bf = *(const short8*)&Wts[m][n * 16 + l15][hi4 * 8];
                acc[m][n] = MFMA16(af, bf, acc[m][n]);
            }
        }
        __builtin_amdgcn_s_setprio(0);
        __syncthreads();
    }

    // epilogue: C-frags (row=4*hi4+r, col=l15) -> LDS; V packed along r
    #pragma unroll
    for (int n = 0; n < 4; ++n) {
        short4v vv;
        #pragma unroll
        for (int r = 0; r < 4; ++r) {
            const int row = wrow + hi4 * 4 + r;
            const int col = n * 16 + l15;
            Qs[row][col] = f2bf(acc[0][n][r]);
            Ks[row][col] = f2bf(acc[1][n][r]);
            vv[r] = (short)f2bf(acc[2][n][r]);
        }
        *(short4v*)&Vts[n * 16 + l15][wrow + hi4 * 4] = vv;
    }
    __syncthreads();

    // ---- group-restricted flash attention (per-wave independent) ----
    int rg[4];
    #pragma unroll
    for (int r = 0; r < 4; ++r) rg[r] = sgid[wrow + hi4 * 4 + r];
    const int klo = glo[sgid[wrow]];
    const int khi = ghi[sgid[wrow + 15]];

    short8 qf[2];
    #pragma unroll
    for (int ks = 0; ks < 2; ++ks)
        qf[ks] = *(const short8*)&Qs[wrow + l15][ks * 32 + hi4 * 8];

    f32x4 o[4];
    float mrun[4], lrun[4];
    #pragma unroll
    for (int n = 0; n < 4; ++n) o[n] = (f32x4){0.f, 0.f, 0.f, 0.f};
    #pragma unroll
    for (int r = 0; r < 4; ++r) { mrun[r] = -3.0e38f; lrun[r] = 0.f; }

    for (int kc = klo & ~63; kc <= khi; kc += 64) {
        f32x4 sfr[4];
        __builtin_amdgcn_s_setprio(1);
        #pragma unroll
        for (int n = 0; n < 4; ++n) {
            const int krow = kc + n * 16 + l15;
            const short8 kf0 = *(const short8*)&Ks[krow][hi4 * 8];
            const short8 kf1 = *(const short8*)&Ks[krow][32 + hi4 * 8];
            f32x4 z = (f32x4){0.f, 0.f, 0.f, 0.f};
            z = MFMA16(qf[0], kf0, z);
            z = MFMA16(qf[1], kf1, z);
            sfr[n] = z;
        }
        __builtin_amdgcn_s_setprio(0);
        int cg[4];
        #pragma unroll
        for (int n = 0; n < 4; ++n) cg[n] = sgid[kc + n * 16 + l15];

        #pragma unroll
        for (int r = 0; r < 4; ++r) {
            const int gr = rg[r];
            float sv[4];
            float smax = -3.0e38f;
            #pragma unroll
            for (int n = 0; n < 4; ++n) {
                float x = sfr[n][r] * 0.125f;       // 1/sqrt(64)
                x = (cg[n] == gr) ? x : -3.0e38f;
                sv[n] = x;
                smax = fmaxf(smax, x);
            }
            smax = fmaxf(smax, __shfl_xor(smax, 1));
            smax = fmaxf(smax, __shfl_xor(smax, 2));
            smax = fmaxf(smax, __shfl_xor(smax, 4));
            smax = fmaxf(smax, __shfl_xor(smax, 8));
            const float newm = fmaxf(mrun[r], smax);
            const float corr = __expf(mrun[r] - newm);
            float ps = 0.f;
            unsigned short pb[4];
            #pragma unroll
            for (int n = 0; n < 4; ++n) {
                const float p = (sv[n] > -1.0e38f) ? __expf(sv[n] - newm) : 0.f;
                ps += p;
                pb[n] = f2bf(p);
            }
            ps += __shfl_xor(ps, 1); ps += __shfl_xor(ps, 2);
            ps += __shfl_xor(ps, 4); ps += __shfl_xor(ps, 8);
            lrun[r] = lrun[r] * corr + ps;
            mrun[r] = newm;
            #pragma unroll
            for (int n = 0; n < 4; ++n) o[n][r] *= corr;
            const int prow = wrow + hi4 * 4 + r;
            #pragma unroll
            for (int n = 0; n < 4; ++n)
                XPs[prow * 72 + n * 16 + l15] = pb[n];
        }

        const short8 pa0 = *(const short8*)&XPs[(wrow + l15) * 72 + hi4 * 8];
        const short8 pa1 = *(const short8*)&XPs[(wrow + l15) * 72 + 32 + hi4 * 8];
        __builtin_amdgcn_s_setprio(1);
        #pragma unroll
        for (int n = 0; n < 4; ++n) {
            const short8 vb0 = *(const short8*)&Vts[n * 16 + l15][kc + hi4 * 8];
            const short8 vb1 = *(const short8*)&Vts[n * 16 + l15][kc + 32 + hi4 * 8];
            o[n] = MFMA16(pa0, vb0, o[n]);
            o[n] = MFMA16(pa1, vb1, o[n]);
        }
        __builtin_amdgcn_s_setprio(0);
    }

    if (abuf) {
        unsigned short* __restrict__ op = abuf + (size_t)t * (256 * 512) + h * 64;
        #pragma unroll
        for (int r = 0; r < 4; ++r) {
            const int row = wrow + hi4 * 4 + r;
            const float inv = 1.0f / lrun[r];
            #pragma unroll
            for (int n = 0; n < 4; ++n)
                op[(size_t)row * 512 + n * 16 + l15] = f2bf(o[n][r] * inv);
        }
    } else {
        float* __restrict__ op = out + (size_t)t * (256 * 512) + h * 64;
        #pragma unroll
        for (int r = 0; r < 4; ++r) {
            const int row = wrow + hi4 * 4 + r;
            const float inv = 1.0f / lrun[r];
            #pragma unroll
            for (int n = 0; n < 4; ++n)
                op[(size_t)row * 512 + n * 16 + l15] = o[n][r] * inv;
        }
    }
}

// ---------------------------------------------------------------------------
// Kernel 2: out = attn @ Wo (f32 out). Block tile 128 x FULL 512 (in-place
// safe when reading f32 attn-out from d_out). 1024 threads = 16 waves (4x4),
// wave tile 32x128, acc 64 VGPR. Register-prefetched staging.
// ---------------------------------------------------------------------------
__global__ __launch_bounds__(1024, 4) void oproj_mfma(
    const float* __restrict__ Wo,             // [512][512] f32
    const unsigned short* __restrict__ wot,   // [512][512] bf16 Wo^T or null
    const unsigned short* __restrict__ abuf,  // bf16 attn-out or null
    float* __restrict__ out)                  // [65536][512]
{
    __shared__ unsigned short As[128 * 40];
    __shared__ unsigned short Bts[512 * 40];

    const int tid  = threadIdx.x;
    const int lane = tid & 63;
    const int w    = tid >> 6;
    const int l15  = lane & 15;
    const int hi4  = lane >> 4;
    const int wr   = w >> 2;    // 0..3 (32-row strip)
    const int wc   = w & 3;     // 0..3 (128-col strip)
    const size_t r0 = (size_t)blockIdx.x * 128;

    f32x4 acc[2][8];
    #pragma unroll
    for (int m = 0; m < 2; ++m)
        #pragma unroll
        for (int n = 0; n < 8; ++n)
            acc[m][n] = (f32x4){0.f, 0.f, 0.f, 0.f};

    const bool isA = tid < 512;
    const int bn = tid & 511;
    const int ai = bn >> 2, aq = bn & 3;

    float4 af0, af1;
    short8 a8;
    short8 b8[4];

    if (isA) {
        if (abuf) {
            a8 = *(const short8*)(abuf + (r0 + ai) * 512 + aq * 8);
        } else {
            const float* s = out + (r0 + ai) * 512 + aq * 8;
            af0 = *(const float4*)s; af1 = *(const float4*)(s + 4);
        }
    } else {
        if (wot) {
            #pragma unroll
            for (int q = 0; q < 4; ++q)
                b8[q] = *(const short8*)(wot + (size_t)bn * 512 + q * 8);
        } else {
            #pragma unroll
            for (int q = 0; q < 4; ++q)
                #pragma unroll
                for (int j = 0; j < 8; ++j)
                    b8[q][j] = (short)f2bf(Wo[(size_t)(q * 8 + j) * 512 + bn]);
        }
    }

    for (int kb = 0; kb < 512; kb += 32) {
        if (isA) *(short8*)&As[ai * 40 + aq * 8] = abuf ? a8 : pack8(af0, af1);
        else {
            #pragma unroll
            for (int q = 0; q < 4; ++q)
                *(short8*)&Bts[bn * 40 + q * 8] = b8[q];
        }
        __syncthreads();
        if (kb < 480) {
            const int kn = kb + 32;
            if (isA) {
                if (abuf) {
                    a8 = *(const short8*)(abuf + (r0 + ai) * 512 + kn + aq * 8);
                } else {
                    const float* s = out + (r0 + ai) * 512 + kn + aq * 8;
                    af0 = *(const float4*)s; af1 = *(const float4*)(s + 4);
                }
            } else {
                if (wot) {
                    #pragma unroll
                    for (int q = 0; q < 4; ++q)
                        b8[q] = *(const short8*)(wot + (size_t)bn * 512 + kn + q * 8);
                } else {
                    #pragma unroll
                    for (int q = 0; q < 4; ++q)
                        #pragma unroll
                        for (int j = 0; j < 8; ++j)
                            b8[q][j] = (short)f2bf(Wo[(size_t)(kn + q * 8 + j) * 512 + bn]);
                }
            }
        }
        short8 afr[2];
        #pragma unroll
        for (int m = 0; m < 2; ++m)
            afr[m] = *(const short8*)&As[(wr * 32 + m * 16 + l15) * 40 + hi4 * 8];
        __builtin_amdgcn_s_setprio(1);
        #pragma unroll
        for (int n = 0; n < 8; ++n) {
            const short8 bfr = *(const short8*)&Bts[(wc * 128 + n * 16 + l15) * 40 + hi4 * 8];
            #pragma unroll
            for (int m = 0; m < 2; ++m)
                acc[m][n] = MFMA16(afr[m], bfr, acc[m][n]);
        }
        __builtin_amdgcn_s_setprio(0);
        __syncthreads();
    }

    #pragma unroll
    for (int m = 0; m < 2; ++m)
        #pragma unroll
        for (int n = 0; n < 8; ++n)
            #pragma unroll
            for (int r = 0; r < 4; ++r)
                out[(r0 + wr * 32 + m * 16 + hi4 * 4 + r) * 512 + wc * 128 + n * 16 + l15] =
                    acc[m][n][r];
}

extern "C" void kernel_launch(void* const* d_in, const int* in_sizes, int n_in,
                              void* d_out, int out_size, void* d_ws, size_t ws_size,
                              hipStream_t stream) {
    const float* hs  = (const float*)d_in[0];
    const int*   gid = (const int*)  d_in[1];
    const float* Wq  = (const float*)d_in[2];
    const float* Wk  = (const float*)d_in[3];
    const float* Wv  = (const float*)d_in[4];
    const float* Wo  = (const float*)d_in[5];
    float* outp = (float*)d_out;

    const size_t WT_SHORTS = (size_t)4 * 512 * 512;          // 2 MB
    const size_t AB_SHORTS = (size_t)256 * 256 * 512;        // 64 M shorts = 128... (67 MB)
    unsigned short* wt   = nullptr;
    unsigned short* wot  = nullptr;
    unsigned short* abuf = nullptr;
    if (ws_size >= WT_SHORTS * 2) {
        wt  = (unsigned short*)d_ws;
        wot = wt + (size_t)3 * 512 * 512;
        wprep<<<256, 256, 0, stream>>>(Wq, Wk, Wv, Wo, wt);
        if (ws_size >= (WT_SHORTS + AB_SHORTS) * 2)
            abuf = wt + WT_SHORTS;
    }

    qkv_attn_mfma<<<2048, 1024, 0, stream>>>(hs, gid, Wq, Wk, Wv, wt, abuf, outp);
    oproj_mfma<<<512, 1024, 0, stream>>>(Wo, wot, abuf, outp);
}

// Round 4
// 318.090 us; speedup vs baseline: 23.6962x; 1.0646x over previous
//
#include <hip/hip_runtime.h>
#include <hip/hip_bf16.h>

typedef __attribute__((ext_vector_type(8))) short short8;
typedef __attribute__((ext_vector_type(4))) short short4v;
typedef __attribute__((ext_vector_type(4))) float f32x4;

#define MFMA16(a, b, c) __builtin_amdgcn_mfma_f32_16x16x32_bf16(a, b, c, 0, 0, 0)

__device__ __forceinline__ unsigned short f2bf(float f) {
    union { __hip_bfloat16 h; unsigned short u; } v;
    v.h = __float2bfloat16(f);
    return v.u;
}

__device__ __forceinline__ short8 pack8(float4 a, float4 b) {
    short8 p;
    p[0] = (short)f2bf(a.x); p[1] = (short)f2bf(a.y);
    p[2] = (short)f2bf(a.z); p[3] = (short)f2bf(a.w);
    p[4] = (short)f2bf(b.x); p[5] = (short)f2bf(b.y);
    p[6] = (short)f2bf(b.z); p[7] = (short)f2bf(b.w);
    return p;
}

// XOR-swizzled LDS indexing (T2, m201): linear rows, byte ^= (row&7)<<4.
// Returns SHORT index. bytecol must be even; XOR touches byte-bits 4..6 only.
__device__ __forceinline__ int swz64(int row, int bytecol) {   // 64-short rows
    return row * 64 + ((bytecol ^ ((row & 7) << 4)) >> 1);
}
__device__ __forceinline__ int swz256(int row, int bytecol) {  // 256-short rows
    return row * 256 + ((bytecol ^ ((row & 7) << 4)) >> 1);
}

// ---------------------------------------------------------------------------
// Weight prep: wt[m][n][k] = W_m[k][n] as bf16, m in {Wq,Wk,Wv,Wo}.
// ---------------------------------------------------------------------------
__global__ __launch_bounds__(256) void wprep(
    const float* __restrict__ Wq, const float* __restrict__ Wk,
    const float* __restrict__ Wv, const float* __restrict__ Wo,
    unsigned short* __restrict__ wt)
{
    __shared__ float tile[64][65];
    const int bid = blockIdx.x;
    const int m = bid >> 6, tb = bid & 63;
    const int kr = (tb >> 3) << 6, nc = (tb & 7) << 6;
    const float* W = (m == 0) ? Wq : (m == 1) ? Wk : (m == 2) ? Wv : Wo;
    const int tid = threadIdx.x;
    for (int i = tid; i < 4096; i += 256)
        tile[i >> 6][i & 63] = W[(size_t)(kr + (i >> 6)) * 512 + nc + (i & 63)];
    __syncthreads();
    unsigned short* dst = wt + (size_t)m * 262144;
    for (int i = tid; i < 4096; i += 256)
        dst[(size_t)(nc + (i >> 6)) * 512 + kr + (i & 63)] = f2bf(tile[i & 63][i >> 6]);
}

// ---------------------------------------------------------------------------
// Kernel 1: fused QKV projection + group-restricted flash attention.
// Block = (t,h), 1024 threads = 16 waves.
// Projection: waves tiled 4 m-groups (64 rows) x 4 n-groups (48 of 192 cols),
// BK=64, reg-prefetched staging, swizzled LDS, 16x16x32 bf16 MFMA.
// Attention: wave w owns rows [16w,16w+16), flash loop over 64-row K chunks
// restricted to the contiguous group range (group_ids sorted).
// ---------------------------------------------------------------------------
__global__ __launch_bounds__(1024, 4) void qkv_attn_mfma(
    const float* __restrict__ hs,   // [256][256][512]
    const int*   __restrict__ gid,  // [256] sorted
    const float* __restrict__ Wq, const float* __restrict__ Wk,
    const float* __restrict__ Wv,
    const unsigned short* __restrict__ wt,   // [3][512][512] bf16 W^T or null
    float*       __restrict__ out)           // [256][256][512] f32 attn-out
{
    __shared__ unsigned short Xs[256 * 64];   // X K-chunk [row][64k]   32 KB
    __shared__ unsigned short Wsh[192 * 64];  // W^T chunk [col][64k]   24 KB
    __shared__ unsigned short Ksh[256 * 64];  // K        [j][64d]      32 KB
    __shared__ unsigned short Vt[64 * 256];   // V^T      [d][256j]     32 KB
    __shared__ unsigned short XP[256 * 64];   // Q transit / P tile     32 KB
    __shared__ int sgid[256];
    __shared__ int glo[16], ghi[16];

    const int bid = blockIdx.x;
    const int h   = (bid & 63) >> 3;
    const int t   = ((bid >> 6) << 3) + (bid & 7);

    const int tid  = threadIdx.x;
    const int lane = tid & 63;
    const int w    = tid >> 6;       // 0..15
    const int l15  = lane & 15;
    const int hi4  = lane >> 4;
    const int mg   = w & 3;          // proj: 64-row group
    const int ng   = w >> 2;         // proj: 48-col group

    if (tid < 16) { glo[tid] = 256; ghi[tid] = -1; }
    __syncthreads();
    if (tid < 256) {
        const int g = gid[tid];
        sgid[tid] = g;
        atomicMin(&glo[g], tid);
        atomicMax(&ghi[g], tid);
    }

    const float* __restrict__ Xbase = hs + (size_t)t * (256 * 512);

    // ---- staging assignments ----
    const int xr = tid >> 2, xq = tid & 3;      // X: row, 16-float quarter
    const bool doW = tid < 768;
    const int wc = tid >> 2;                    // W: global col 0..191
    const int wq = tid & 3;                     // 16-elem quarter of 64 k
    const int wmat = wc >> 6, wcol = wc & 63;
    const unsigned short* __restrict__ wsrc =
        wt ? wt + ((size_t)wmat * 512 + h * 64 + wcol) * 512 : nullptr;
    const float* __restrict__ wfsrc =
        (wmat == 0) ? Wq : (wmat == 1) ? Wk : Wv;

    f32x4 acc[4][3];
    #pragma unroll
    for (int mt = 0; mt < 4; ++mt)
        #pragma unroll
        for (int nt = 0; nt < 3; ++nt)
            acc[mt][nt] = (f32x4){0.f, 0.f, 0.f, 0.f};

    float4 xf[4];
    short8 w8[2];
    {
        const float* s = Xbase + (size_t)xr * 512 + xq * 16;
        xf[0] = *(const float4*)(s + 0);  xf[1] = *(const float4*)(s + 4);
        xf[2] = *(const float4*)(s + 8);  xf[3] = *(const float4*)(s + 12);
        if (doW) {
            if (wt) {
                w8[0] = *(const short8*)(wsrc + wq * 16);
                w8[1] = *(const short8*)(wsrc + wq * 16 + 8);
            } else {
                #pragma unroll
                for (int b = 0; b < 2; ++b)
                    #pragma unroll
                    for (int j = 0; j < 8; ++j)
                        w8[b][j] = (short)f2bf(
                            wfsrc[(size_t)(wq * 16 + b * 8 + j) * 512 + h * 64 + wcol]);
            }
        }
    }

    for (int kb = 0; kb < 512; kb += 64) {
        // ---- post staged regs to LDS (swizzled) ----
        *(short8*)&Xs[swz64(xr, xq * 32 + 0)]  = pack8(xf[0], xf[1]);
        *(short8*)&Xs[swz64(xr, xq * 32 + 16)] = pack8(xf[2], xf[3]);
        if (doW) {
            *(short8*)&Wsh[swz64(wc, wq * 32 + 0)]  = w8[0];
            *(short8*)&Wsh[swz64(wc, wq * 32 + 16)] = w8[1];
        }
        __syncthreads();
        // ---- prefetch next chunk ----
        if (kb < 448) {
            const int kn = kb + 64;
            const float* s = Xbase + (size_t)xr * 512 + kn + xq * 16;
            xf[0] = *(const float4*)(s + 0);  xf[1] = *(const float4*)(s + 4);
            xf[2] = *(const float4*)(s + 8);  xf[3] = *(const float4*)(s + 12);
            if (doW) {
                if (wt) {
                    w8[0] = *(const short8*)(wsrc + kn + wq * 16);
                    w8[1] = *(const short8*)(wsrc + kn + wq * 16 + 8);
                } else {
                    #pragma unroll
                    for (int b = 0; b < 2; ++b)
                        #pragma unroll
                        for (int j = 0; j < 8; ++j)
                            w8[b][j] = (short)f2bf(
                                wfsrc[(size_t)(kn + wq * 16 + b * 8 + j) * 512 + h * 64 + wcol]);
                }
            }
        }
        // ---- MFMA phase: 24 MFMA, 14 ds_read_b128 ----
        #pragma unroll
        for (int ks = 0; ks < 2; ++ks) {
            short8 af[4];
            #pragma unroll
            for (int mt = 0; mt < 4; ++mt)
                af[mt] = *(const short8*)&Xs[swz64(mg * 64 + mt * 16 + l15,
                                                   ks * 64 + hi4 * 16)];
            __builtin_amdgcn_s_setprio(1);
            #pragma unroll
            for (int nt = 0; nt < 3; ++nt) {
                const short8 bf = *(const short8*)&Wsh[swz64(ng * 48 + nt * 16 + l15,
                                                             ks * 64 + hi4 * 16)];
                #pragma unroll
                for (int mt = 0; mt < 4; ++mt)
                    acc[mt][nt] = MFMA16(af[mt], bf, acc[mt][nt]);
            }
            __builtin_amdgcn_s_setprio(0);
        }
        __syncthreads();
    }

    // ---- epilogue: route C-frags (row=4*hi4+r, col=l15) to Q/K/V LDS ----
    #pragma unroll
    for (int nt = 0; nt < 3; ++nt) {
        const int c0 = (ng * 3 + nt) * 16;     // global col of tile
        const int m  = c0 >> 6;                // which matrix
        const int d0 = c0 & 63;                // col within head-dim
        #pragma unroll
        for (int mt = 0; mt < 4; ++mt) {
            const int rowb = mg * 64 + mt * 16 + hi4 * 4;
            if (m == 0) {
                #pragma unroll
                for (int r = 0; r < 4; ++r)
                    XP[swz64(rowb + r, (d0 + l15) * 2)] = f2bf(acc[mt][nt][r]);
            } else if (m == 1) {
                #pragma unroll
                for (int r = 0; r < 4; ++r)
                    Ksh[swz64(rowb + r, (d0 + l15) * 2)] = f2bf(acc[mt][nt][r]);
            } else {
                short4v vv;
                #pragma unroll
                for (int r = 0; r < 4; ++r) vv[r] = (short)f2bf(acc[mt][nt][r]);
                *(short4v*)&Vt[swz256(d0 + l15, rowb * 2)] = vv;
            }
        }
    }
    __syncthreads();

    // ---- group-restricted flash attention; wave owns rows [16w,16w+16) ----
    const int wrow = w << 4;
    int rg[4];
    #pragma unroll
    for (int r = 0; r < 4; ++r) rg[r] = sgid[wrow + hi4 * 4 + r];
    const int klo = glo[sgid[wrow]];
    const int khi = ghi[sgid[wrow + 15]];

    short8 qf[2];
    #pragma unroll
    for (int ks = 0; ks < 2; ++ks)
        qf[ks] = *(const short8*)&XP[swz64(wrow + l15, ks * 64 + hi4 * 16)];

    f32x4 o[4];
    float mrun[4], lrun[4];
    #pragma unroll
    for (int n = 0; n < 4; ++n) o[n] = (f32x4){0.f, 0.f, 0.f, 0.f};
    #pragma unroll
    for (int r = 0; r < 4; ++r) { mrun[r] = -3.0e38f; lrun[r] = 0.f; }

    for (int kc = klo & ~63; kc <= khi; kc += 64) {
        f32x4 sfr[4];
        __builtin_amdgcn_s_setprio(1);
        #pragma unroll
        for (int n = 0; n < 4; ++n) {
            const int krow = kc + n * 16 + l15;
            const short8 kf0 = *(const short8*)&Ksh[swz64(krow, hi4 * 16)];
            const short8 kf1 = *(const short8*)&Ksh[swz64(krow, 64 + hi4 * 16)];
            f32x4 z = (f32x4){0.f, 0.f, 0.f, 0.f};
            z = MFMA16(qf[0], kf0, z);
            z = MFMA16(qf[1], kf1, z);
            sfr[n] = z;
        }
        __builtin_amdgcn_s_setprio(0);
        int cg[4];
        #pragma unroll
        for (int n = 0; n < 4; ++n) cg[n] = sgid[kc + n * 16 + l15];

        #pragma unroll
        for (int r = 0; r < 4; ++r) {
            const int gr = rg[r];
            float sv[4];
            float smax = -3.0e38f;
            #pragma unroll
            for (int n = 0; n < 4; ++n) {
                float x = sfr[n][r] * 0.125f;       // 1/sqrt(64)
                x = (cg[n] == gr) ? x : -3.0e38f;
                sv[n] = x;
                smax = fmaxf(smax, x);
            }
            smax = fmaxf(smax, __shfl_xor(smax, 1));
            smax = fmaxf(smax, __shfl_xor(smax, 2));
            smax = fmaxf(smax, __shfl_xor(smax, 4));
            smax = fmaxf(smax, __shfl_xor(smax, 8));
            const float newm = fmaxf(mrun[r], smax);
            const float corr = __expf(mrun[r] - newm);
            float ps = 0.f;
            unsigned short pb[4];
            #pragma unroll
            for (int n = 0; n < 4; ++n) {
                const float p = (sv[n] > -1.0e38f) ? __expf(sv[n] - newm) : 0.f;
                ps += p;
                pb[n] = f2bf(p);
            }
            ps += __shfl_xor(ps, 1); ps += __shfl_xor(ps, 2);
            ps += __shfl_xor(ps, 4); ps += __shfl_xor(ps, 8);
            lrun[r] = lrun[r] * corr + ps;
            mrun[r] = newm;
            #pragma unroll
            for (int n = 0; n < 4; ++n) o[n][r] *= corr;
            const int prow = wrow + hi4 * 4 + r;
            #pragma unroll
            for (int n = 0; n < 4; ++n)
                XP[swz64(prow, (n * 16 + l15) * 2)] = pb[n];
        }

        const short8 pa0 = *(const short8*)&XP[swz64(wrow + l15, hi4 * 16)];
        const short8 pa1 = *(const short8*)&XP[swz64(wrow + l15, 64 + hi4 * 16)];
        __builtin_amdgcn_s_setprio(1);
        #pragma unroll
        for (int n = 0; n < 4; ++n) {
            const short8 vb0 = *(const short8*)&Vt[swz256(n * 16 + l15, (kc + hi4 * 8) * 2)];
            const short8 vb1 = *(const short8*)&Vt[swz256(n * 16 + l15, (kc + 32 + hi4 * 8) * 2)];
            o[n] = MFMA16(pa0, vb0, o[n]);
            o[n] = MFMA16(pa1, vb1, o[n]);
        }
        __builtin_amdgcn_s_setprio(0);
    }

    float* __restrict__ op = out + (size_t)t * (256 * 512) + h * 64;
    #pragma unroll
    for (int r = 0; r < 4; ++r) {
        const int row = wrow + hi4 * 4 + r;
        const float inv = 1.0f / lrun[r];
        #pragma unroll
        for (int n = 0; n < 4; ++n)
            op[(size_t)row * 512 + n * 16 + l15] = o[n][r] * inv;
    }
}

// ---------------------------------------------------------------------------
// Kernel 2: out = attn @ Wo (f32, in-place over d_out). Block tile 128 x 512.
// ---------------------------------------------------------------------------
__global__ __launch_bounds__(1024, 4) void oproj_mfma(
    const float* __restrict__ Wo,             // [512][512] f32
    const unsigned short* __restrict__ wot,   // [512][512] bf16 Wo^T or null
    float* __restrict__ out)                  // [65536][512]
{
    __shared__ unsigned short As[128 * 40];
    __shared__ unsigned short Bts[512 * 40];

    const int tid  = threadIdx.x;
    const int lane = tid & 63;
    const int w    = tid >> 6;
    const int l15  = lane & 15;
    const int hi4  = lane >> 4;
    const int wr   = w >> 2;
    const int wc   = w & 3;
    const size_t r0 = (size_t)blockIdx.x * 128;

    f32x4 acc[2][8];
    #pragma unroll
    for (int m = 0; m < 2; ++m)
        #pragma unroll
        for (int n = 0; n < 8; ++n)
            acc[m][n] = (f32x4){0.f, 0.f, 0.f, 0.f};

    const bool isA = tid < 512;
    const int bn = tid & 511;
    const int ai = bn >> 2, aq = bn & 3;

    float4 af0, af1;
    short8 b8[4];

    if (isA) {
        const float* s = out + (r0 + ai) * 512 + aq * 8;
        af0 = *(const float4*)s; af1 = *(const float4*)(s + 4);
    } else {
        if (wot) {
            #pragma unroll
            for (int q = 0; q < 4; ++q)
                b8[q] = *(const short8*)(wot + (size_t)bn * 512 + q * 8);
        } else {
            #pragma unroll
            for (int q = 0; q < 4; ++q)
                #pragma unroll
                for (int j = 0; j < 8; ++j)
                    b8[q][j] = (short)f2bf(Wo[(size_t)(q * 8 + j) * 512 + bn]);
        }
    }

    for (int kb = 0; kb < 512; kb += 32) {
        if (isA) *(short8*)&As[ai * 40 + aq * 8] = pack8(af0, af1);
        else {
            #pragma unroll
            for (int q = 0; q < 4; ++q)
                *(short8*)&Bts[bn * 40 + q * 8] = b8[q];
        }
        __syncthreads();
        if (kb < 480) {
            const int kn = kb + 32;
            if (isA) {
                const float* s = out + (r0 + ai) * 512 + kn + aq * 8;
                af0 = *(const float4*)s; af1 = *(const float4*)(s + 4);
            } else {
                if (wot) {
                    #pragma unroll
                    for (int q = 0; q < 4; ++q)
                        b8[q] = *(const short8*)(wot + (size_t)bn * 512 + kn + q * 8);
                } else {
                    #pragma unroll
                    for (int q = 0; q < 4; ++q)
                        #pragma unroll
                        for (int j = 0; j < 8; ++j)
                            b8[q][j] = (short)f2bf(Wo[(size_t)(kn + q * 8 + j) * 512 + bn]);
                }
            }
        }
        short8 afr[2];
        #pragma unroll
        for (int m = 0; m < 2; ++m)
            afr[m] = *(const short8*)&As[(wr * 32 + m * 16 + l15) * 40 + hi4 * 8];
        __builtin_amdgcn_s_setprio(1);
        #pragma unroll
        for (int n = 0; n < 8; ++n) {
            const short8 bfr = *(const short8*)&Bts[(wc * 128 + n * 16 + l15) * 40 + hi4 * 8];
            #pragma unroll
            for (int m = 0; m < 2; ++m)
                acc[m][n] = MFMA16(afr[m], bfr, acc[m][n]);
        }
        __builtin_amdgcn_s_setprio(0);
        __syncthreads();
    }

    #pragma unroll
    for (int m = 0; m < 2; ++m)
        #pragma unroll
        for (int n = 0; n < 8; ++n)
            #pragma unroll
            for (int r = 0; r < 4; ++r)
                out[(r0 + wr * 32 + m * 16 + hi4 * 4 + r) * 512 + wc * 128 + n * 16 + l15] =
                    acc[m][n][r];
}

extern "C" void kernel_launch(void* const* d_in, const int* in_sizes, int n_in,
                              void* d_out, int out_size, void* d_ws, size_t ws_size,
                              hipStream_t stream) {
    const float* hs  = (const float*)d_in[0];
    const int*   gid = (const int*)  d_in[1];
    const float* Wq  = (const float*)d_in[2];
    const float* Wk  = (const float*)d_in[3];
    const float* Wv  = (const float*)d_in[4];
    const float* Wo  = (const float*)d_in[5];
    float* outp = (float*)d_out;

    unsigned short* wt  = nullptr;
    unsigned short* wot = nullptr;
    if (ws_size >= (size_t)4 * 512 * 512 * 2) {   // 2 MB
        wt  = (unsigned short*)d_ws;
        wot = wt + (size_t)3 * 512 * 512;
        wprep<<<256, 256, 0, stream>>>(Wq, Wk, Wv, Wo, wt);
    }

    qkv_attn_mfma<<<2048, 1024, 0, stream>>>(hs, gid, Wq, Wk, Wv, wt, outp);
    oproj_mfma<<<512, 1024, 0, stream>>>(Wo, wot, outp);
}